// Round 9
// baseline (233.841 us; speedup 1.0000x reference)
//
#include <hip/hip_runtime.h>
#include <hip/hip_bf16.h>

// ---------------------------------------------------------------------------
// QuixerCore: 10-qubit QSVT/LCU quantum circuit simulator.
// R3: phased-LDS PQC. R4: tiled params GEMM. R5: v2f packed gate math.
// R6: product-state init (step1 skips 10 RYs). R7: angle prefetch.
// R9: TEMPORAL dual-token pipeline in the steps: one wave runs two tokens
//     through ONE 8KB slab, remap drains of token A covered by gates of
//     token B (per-wave in-order LDS retirement makes slab reuse safe).
//     Occupancy stays 20 waves/CU (R8's spatial-dual halved it -> regressed).
//     Final keeps LDS-transpose measurement (R8), 4 partial slices.
// Canonical layout: n = r*64+lane, wire w at bit 9-w.
// P2 layout: lane bits 0..5 = wires 5,4,6,7,2,3 ; reg bits 6..9 = wires 8,9,0,1.
// P8 layout: wire->bit: w0=1, w1=0, w>=2: bit w.
// ---------------------------------------------------------------------------

#define NQ   10
#define NT   32
#define DM   512
#define BATCH 128
#define NPQC 40
#define DIM  1024
#define NROWS (BATCH * NT)    // 4096
#define PSTRIDE (BATCH * DIM) // elements per partial slice (v2f)

typedef float v2f __attribute__((ext_vector_type(2)));

#define WAITLDS asm volatile("s_waitcnt lgkmcnt(0)" ::: "memory")

__device__ __forceinline__ v2f Jrot(v2f v) {   // (v.y, -v.x)
  return __builtin_shufflevector(v, -v, 1, 2);
}
__device__ __forceinline__ v2f Jc(v2f v) {     // (-v.y, v.x)
  return __builtin_shufflevector(-v, v, 1, 2);
}

// ------------------------- gate primitives ---------------------------------

template<int B>
__device__ __forceinline__ void g_ry(v2f (&a)[16], float c, float s) {
  static_assert(B >= 6, "RY targets must be register bits");
  constexpr int m = 1 << (B - 6);
#pragma unroll
  for (int r = 0; r < 16; ++r) {
    if (!(r & m)) {
      int r1 = r | m;
      v2f a0 = a[r], a1 = a[r1];
      a[r]  = c * a0 - s * a1;
      a[r1] = s * a0 + c * a1;
    }
  }
}

template<int BC, int BT>
__device__ __forceinline__ void g_crx(v2f (&a)[16], int lane, float c, float s) {
  static_assert(BT >= 6, "CRX targets must be register bits");
  constexpr int m = 1 << (BT - 6);
  bool lane_ok = (BC >= 6) || ((lane >> BC) & 1);
  float ce = lane_ok ? c : 1.f;
  float se = lane_ok ? s : 0.f;
#pragma unroll
  for (int r = 0; r < 16; ++r) {
    if (!(r & m)) {
      if constexpr (BC >= 6) { if (!((r >> (BC - 6)) & 1)) continue; }
      int r1 = r | m;
      v2f a0 = a[r], a1 = a[r1];
      a[r]  = ce * a0 + se * Jrot(a1);
      a[r1] = ce * a1 + se * Jrot(a0);
    }
  }
}

// ------------------------- layout remap (split w/r) ------------------------
template<int L0, int L1, int L2, int L3>
__device__ __forceinline__ void remap_w(const v2f (&a)[16],
                                        v2f* __restrict__ slab, int lane) {
#pragma unroll
  for (int r = 0; r < 16; ++r) {
    int f = 0;
    if (L0 < 4 && (r & 1)) f |= 1 << L0;
    if (L1 < 4 && (r & 2)) f |= 1 << L1;
    if (L2 < 4 && (r & 4)) f |= 1 << L2;
    if (L3 < 4 && (r & 8)) f |= 1 << L3;
    slab[r * 64 + (lane ^ f)] = a[r];
  }
}

template<int L0, int L1, int L2, int L3>
__device__ __forceinline__ void remap_r(v2f (&a)[16],
                                        const v2f* __restrict__ slab, int lane) {
  constexpr int LM = (1 << L0) | (1 << L1) | (1 << L2) | (1 << L3);
  int la = lane & ~LM & 63;
  la |= ((lane >> L0) & 1) << 6;
  la |= ((lane >> L1) & 1) << 7;
  la |= ((lane >> L2) & 1) << 8;
  la |= ((lane >> L3) & 1) << 9;
  if (L0 < 4) la |= ((lane >> L0) & 1) << L0;
  if (L1 < 4) la |= ((lane >> L1) & 1) << L1;
  if (L2 < 4) la |= ((lane >> L2) & 1) << L2;
  if (L3 < 4) la |= ((lane >> L3) & 1) << L3;
#pragma unroll
  for (int r = 0; r < 16; ++r) {
    int rc = ((r & 1) ? (1 << L0) : 0) | ((r & 2) ? (1 << L1) : 0)
           | ((r & 4) ? (1 << L2) : 0) | ((r & 8) ? (1 << L3) : 0);
    a[r] = slab[la ^ rc];
  }
}

// combined remap (final kernel)
template<int L0, int L1, int L2, int L3>
__device__ __forceinline__ void remap(v2f (&a)[16], v2f* __restrict__ slab,
                                      int lane) {
  remap_w<L0, L1, L2, L3>(a, slab, lane);
  WAITLDS;
  remap_r<L0, L1, L2, L3>(a, slab, lane);
}

// remap index -> lane-bit set (ledger)
template<int I> struct RL;
template<> struct RL<0> { static constexpr int A=5,B=4,C=3,D=2; };
template<> struct RL<1> { static constexpr int A=1,B=0,C=2,D=3; };
template<> struct RL<2> { static constexpr int A=1,B=0,C=2,D=3; };
template<> struct RL<3> { static constexpr int A=2,B=3,C=4,D=5; };
template<> struct RL<4> { static constexpr int A=2,B=3,C=4,D=5; };
template<> struct RL<5> { static constexpr int A=1,B=0,C=2,D=3; };
template<> struct RL<6> { static constexpr int A=4,B=5,C=1,D=0; };
template<> struct RL<7> { static constexpr int A=2,B=3,C=4,D=5; };

template<int I>
__device__ __forceinline__ void rmw(const v2f (&a)[16], v2f* __restrict__ slab,
                                    int lane) {
  remap_w<RL<I>::A, RL<I>::B, RL<I>::C, RL<I>::D>(a, slab, lane);
}
template<int I>
__device__ __forceinline__ void rmr(v2f (&a)[16], const v2f* __restrict__ slab,
                                    int lane) {
  remap_r<RL<I>::A, RL<I>::B, RL<I>::C, RL<I>::D>(a, slab, lane);
}

// ------------------------- per-phase gates ---------------------------------
// Phase i gates, executed in the layout established by remap i-1.
template<int PH, bool SKIP_HEAD>
__device__ __forceinline__ void phase_gates(v2f (&a)[16],
    const float2* __restrict__ cs, int lane) {
  float2 t;
#define RYk(B_, k)      t = cs[k]; g_ry<B_>(a, t.x, t.y);
#define CXk(BC, BT, k)  t = cs[k]; g_crx<BC, BT>(a, lane, t.x, t.y);
  if constexpr (PH == 0) { RYk(9,0) RYk(8,1) RYk(7,2) RYk(6,3) }
  else if constexpr (PH == 1) { RYk(6,4) RYk(7,5) RYk(8,6) RYk(9,7) }
  else if constexpr (PH == 2) {
    if constexpr (!SKIP_HEAD) { RYk(6,8) RYk(7,9) }
    CXk(7,8,10) CXk(6,7,11) CXk(3,6,12)
  }
  else if constexpr (PH == 3) { CXk(8,9,13) CXk(7,8,14) CXk(6,7,15) CXk(5,6,16) }
  else if constexpr (PH == 4) { CXk(8,9,17) CXk(7,8,18) CXk(6,7,19)
                                RYk(6,20) RYk(7,21) RYk(8,22) RYk(9,23) }
  else if constexpr (PH == 5) { RYk(6,24) RYk(7,25) RYk(8,26) RYk(9,27) }
  else if constexpr (PH == 6) { RYk(6,28) RYk(7,29)
                                CXk(7,6,30) CXk(8,7,31) CXk(9,8,32) CXk(4,9,33) }
  else if constexpr (PH == 7) { CXk(7,6,34) CXk(8,7,35) CXk(9,8,36) CXk(2,9,37) }
  else { CXk(7,6,38) CXk(8,7,39) }
#undef RYk
#undef CXk
}

// ------------------------- temporal-dual PQC -------------------------------
// Two tokens through ONE slab; drains of one token covered by gates of the
// other. Safe because a wave's LDS ops retire in order (write-after-read to
// the slab needs no wait).
template<bool SKIP_HEAD>
__device__ __forceinline__ void apply_pqc_dual(v2f (&A)[16], v2f (&B)[16],
    const float2* __restrict__ csA, const float2* __restrict__ csB,
    v2f* __restrict__ slab, int lane) {
#define STEP_PAIR(i, ip1) \
  phase_gates<ip1, SKIP_HEAD>(A, csA, lane); \
  WAITLDS; rmr<i>(B, slab, lane); rmw<ip1>(A, slab, lane); \
  phase_gates<ip1, SKIP_HEAD>(B, csB, lane); \
  WAITLDS; rmr<ip1>(A, slab, lane); rmw<ip1>(B, slab, lane);
  if constexpr (!SKIP_HEAD) {
    phase_gates<0, false>(A, csA, lane);
    rmw<0>(A, slab, lane);
    phase_gates<0, false>(B, csB, lane);
    WAITLDS; rmr<0>(A, slab, lane); rmw<0>(B, slab, lane);
    STEP_PAIR(0, 1)
    STEP_PAIR(1, 2)
  } else {
    // enter at P2 tail (states pre-built in P2 by product_init)
    phase_gates<2, true>(A, csA, lane);
    rmw<2>(A, slab, lane);
    phase_gates<2, true>(B, csB, lane);
    WAITLDS; rmr<2>(A, slab, lane); rmw<2>(B, slab, lane);
  }
  STEP_PAIR(2, 3)
  STEP_PAIR(3, 4)
  STEP_PAIR(4, 5)
  STEP_PAIR(5, 6)
  STEP_PAIR(6, 7)
  phase_gates<8, SKIP_HEAD>(A, csA, lane);
  WAITLDS; rmr<7>(B, slab, lane);
  phase_gates<8, SKIP_HEAD>(B, csB, lane);
#undef STEP_PAIR
}

// single-state phased PQC (final kernel)
__device__ __forceinline__ void apply_pqc_single(v2f (&a)[16],
    const float2* __restrict__ cs, v2f* __restrict__ slab, int lane) {
  phase_gates<0, false>(a, cs, lane);
  remap<RL<0>::A, RL<0>::B, RL<0>::C, RL<0>::D>(a, slab, lane);
  phase_gates<1, false>(a, cs, lane);
  remap<RL<1>::A, RL<1>::B, RL<1>::C, RL<1>::D>(a, slab, lane);
  phase_gates<2, false>(a, cs, lane);
  remap<RL<2>::A, RL<2>::B, RL<2>::C, RL<2>::D>(a, slab, lane);
  phase_gates<3, false>(a, cs, lane);
  remap<RL<3>::A, RL<3>::B, RL<3>::C, RL<3>::D>(a, slab, lane);
  phase_gates<4, false>(a, cs, lane);
  remap<RL<4>::A, RL<4>::B, RL<4>::C, RL<4>::D>(a, slab, lane);
  phase_gates<5, false>(a, cs, lane);
  remap<RL<5>::A, RL<5>::B, RL<5>::C, RL<5>::D>(a, slab, lane);
  phase_gates<6, false>(a, cs, lane);
  remap<RL<6>::A, RL<6>::B, RL<6>::C, RL<6>::D>(a, slab, lane);
  phase_gates<7, false>(a, cs, lane);
  remap<RL<7>::A, RL<7>::B, RL<7>::C, RL<7>::D>(a, slab, lane);
  phase_gates<8, false>(a, cs, lane);
}

__device__ __forceinline__ int p8_lane_canon(int lane) {
  return (((lane >> 1) & 1) << 9) | ((lane & 1) << 8) | (((lane >> 2) & 1) << 7)
       | (((lane >> 3) & 1) << 6) | (((lane >> 4) & 1) << 5) | (((lane >> 5) & 1) << 4);
}

// product state in P2 layout from one cs row (10 RYs applied to |0>)
__device__ __forceinline__ void product_init(v2f (&a)[16],
    const float2* __restrict__ csrow, int lane) {
  float2 f5 = csrow[5], f4 = csrow[4], f6 = csrow[6], f7 = csrow[7];
  float2 f2 = csrow[2], f3 = csrow[3];
  float2 f8 = csrow[8], f9 = csrow[9], f0 = csrow[0], f1 = csrow[1];
  float lp = ((lane & 1) ? f5.y : f5.x);
  lp *= ((lane & 2) ? f4.y : f4.x);
  lp *= ((lane & 4) ? f6.y : f6.x);
  lp *= ((lane & 8) ? f7.y : f7.x);
  lp *= ((lane & 16) ? f2.y : f2.x);
  lp *= ((lane & 32) ? f3.y : f3.x);
#pragma unroll
  for (int r = 0; r < 16; ++r) {
    float rp = ((r & 1) ? f8.y : f8.x) * ((r & 2) ? f9.y : f9.x)
             * ((r & 4) ? f0.y : f0.x) * ((r & 8) ? f1.y : f1.x);
    a[r].x = lp * rp;
    a[r].y = 0.f;
  }
}

// ------------------------- params: register-tiled GEMM ----------------------
__global__ __launch_bounds__(256) void params_kernel(
    const float* __restrict__ emb, const float* __restrict__ W,
    const float* __restrict__ bias,
    const float* __restrict__ lcu_re, const float* __restrict__ lcu_im,
    const float* __restrict__ ffp,
    float2* __restrict__ cs, float2* __restrict__ ffcs, float2* __restrict__ lcu) {
  int blk = blockIdx.x;
  int tid = threadIdx.x;
  if (blk == 256) {
    if (tid < NPQC) {
      float h = 0.5f * ffp[tid];
      ffcs[tid] = make_float2(cosf(h), sinf(h));
    }
    if (tid == 64) {
      float ssum = 0.f;
      for (int i = 0; i < NT; ++i) {
        float re = lcu_re[i], im = lcu_im[i];
        ssum += sqrtf(re * re + im * im);
      }
      float inv = 1.f / ssum;
      for (int i = 0; i < NT; ++i)
        lcu[i] = make_float2(lcu_re[i] * inv, lcu_im[i] * inv);
    }
    return;
  }

  __shared__ float Asl[16 * 516];   // 33 KB; reused as reduction buffer
  int row0 = blk * 16;

  const float4* eg = (const float4*)(emb + (size_t)row0 * DM);
#pragma unroll
  for (int i = 0; i < 8; ++i) {
    int e = tid + i * 256;
    int r = e >> 7, k4 = e & 127;
    float4 v = eg[e];
    *(float4*)&Asl[r * 516 + k4 * 4] = v;
  }
  __syncthreads();

  int kq = tid >> 6;
  int lane = tid & 63;
  int rg = lane >> 3;
  int cg = lane & 7;

  const float* Ar0 = &Asl[(2 * rg) * 516 + kq * 128];
  const float* Ar1 = Ar0 + 516;
  const float* Bg  = W + (size_t)(5 * cg) * DM + kq * 128;

  float acc[2][5] = {};
#pragma unroll 4
  for (int k = 0; k < 128; k += 4) {
    float4 a0 = *(const float4*)(Ar0 + k);
    float4 a1 = *(const float4*)(Ar1 + k);
#pragma unroll
    for (int j = 0; j < 5; ++j) {
      float4 b = *(const float4*)(Bg + j * DM + k);
      acc[0][j] += a0.x * b.x + a0.y * b.y + a0.z * b.z + a0.w * b.w;
      acc[1][j] += a1.x * b.x + a1.y * b.y + a1.z * b.z + a1.w * b.w;
    }
  }

  __syncthreads();
  float* red = Asl;
#pragma unroll
  for (int i = 0; i < 2; ++i)
#pragma unroll
    for (int j = 0; j < 5; ++j)
      red[kq * 644 + (2 * rg + i) * 40 + 5 * cg + j] = acc[i][j];
  __syncthreads();

  for (int o = tid; o < 640; o += 256) {
    float v = bias[o % 40] + red[o] + red[644 + o] + red[1288 + o] + red[1932 + o];
    float h = 0.5f * v;
    cs[(size_t)blk * 640 + o] = make_float2(cosf(h), sinf(h));
  }
}

// ------------------------- QSVT step (temporal dual) -----------------------
// grid = 512 (b = blk>>2, slice qq = blk&3), block = 256 = 4 waves.
// Wave wv handles tokens l0 = qq*8 + wv*2 and l0+1 through ONE 8KB slab.
// LDS 32KB/block -> 5 blocks (20 waves)/CU; 2048 waves, single round.
template<bool FIRST>
__global__ __launch_bounds__(256) void pqc_step(
    const float2* __restrict__ cs, const float2* __restrict__ lcu,
    const v2f* __restrict__ src, v2f* __restrict__ dst) {
  __shared__ v2f slabs[4][1024];   // 32 KB
  int lane = threadIdx.x & 63;
  int wvu = __builtin_amdgcn_readfirstlane(threadIdx.x >> 6);
  int blk = blockIdx.x;
  int b = blk >> 2, qq = blk & 3;
  int l0 = qq * 8 + wvu * 2;
  const float2* csA = cs + (size_t)(b * NT + l0) * NPQC;
  const float2* csB = csA + NPQC;
  v2f* slab = slabs[wvu];

  v2f A[16], B[16];
  if constexpr (FIRST) {
    product_init(A, csA, lane);
    product_init(B, csB, lane);
  } else {
    const v2f* s = src + (size_t)b * DIM;
#pragma unroll
    for (int r = 0; r < 16; ++r) {
      int n = r * 64 + lane;
      v2f acc = s[n] + s[n + PSTRIDE] + s[n + 2 * PSTRIDE] + s[n + 3 * PSTRIDE];
      A[r] = acc;
      B[r] = acc;      // same input state for both tokens
    }
  }

  apply_pqc_dual<FIRST>(A, B, csA, csB, slab, lane);

  // weighted combine of both tokens -> own slab at canonical swizzled index
  float2 wA = lcu[l0], wB = lcu[l0 + 1];
  int pl = p8_lane_canon(lane);
  pl ^= (pl >> 5);
#pragma unroll
  for (int r = 0; r < 16; ++r) {
    int rc = ((r & 1) << 3) | ((r & 2) << 1) | ((r & 4) >> 1) | ((r & 8) >> 3); // rev4
    slab[pl ^ rc] = wA.x * A[r] + wA.y * Jc(A[r])
                  + wB.x * B[r] + wB.y * Jc(B[r]);
  }
  __syncthreads();

  // reduce 4 wave-slabs -> global partial slice (canonical layout)
  v2f* dst_b = dst + (size_t)(qq * BATCH + b) * DIM;
#pragma unroll
  for (int i = 0; i < 4; ++i) {
    int n = threadIdx.x + i * 256;
    int ph = n ^ (n >> 5);
    v2f sum = slabs[0][ph] + slabs[1][ph] + slabs[2][ph] + slabs[3][ph];
    dst_b[n] = sum;
  }
}

// ------------------------- final -------------------------------------------
// 32 blocks x 4 waves (wave = one batch element). LDS-transpose measurement.
__global__ __launch_bounds__(256) void final_kernel(
    const v2f* __restrict__ part1, const v2f* __restrict__ part2,
    const float* __restrict__ qsvt, const float2* __restrict__ ffcs,
    float* __restrict__ out) {
  __shared__ v2f slabs[4][1024];   // 32 KB
  int lane = threadIdx.x & 63;
  int wvu = __builtin_amdgcn_readfirstlane(threadIdx.x >> 6);
  int b = blockIdx.x * 4 + wvu;
  float q0 = qsvt[0], q1 = qsvt[1], q2 = qsvt[2];

  v2f a[16];
  const v2f* p1 = part1 + (size_t)b * DIM;
  const v2f* p2 = part2 + (size_t)b * DIM;
#pragma unroll
  for (int r = 0; r < 16; ++r) {
    int n = r * 64 + lane;
    v2f m1 = (v2f)(0.f), m2 = (v2f)(0.f);
#pragma unroll
    for (int q = 0; q < 4; ++q) {
      m1 += p1[n + q * PSTRIDE];
      m2 += p2[n + q * PSTRIDE];
    }
    a[r] = q1 * m1 + q2 * m2;
  }
  if (lane == 0) a[0].x += q0;

  float nn = 0.f;
#pragma unroll
  for (int r = 0; r < 16; ++r) nn += a[r].x * a[r].x + a[r].y * a[r].y;
#pragma unroll
  for (int o = 1; o < 64; o <<= 1) nn += __shfl_xor(nn, o);
  float inv = 1.f / sqrtf(nn);
#pragma unroll
  for (int r = 0; r < 16; ++r) a[r] *= inv;

  apply_pqc_single(a, ffcs, slabs[wvu], lane);

  // per-lane partials: prt[w]=X, prt[10+w]=Y, prt[20+w]=Z  (P8 layout)
  constexpr int BPOS[10] = {1, 0, 2, 3, 4, 5, 6, 7, 8, 9};
  float prt[30];
#pragma unroll
  for (int w = 0; w < NQ; ++w) {
    const int p = BPOS[w];
    float xr = 0.f, xi = 0.f, zz = 0.f;
    if (p >= 6) {
      const int m = 1 << (p - 6);
#pragma unroll
      for (int r = 0; r < 16; ++r) {
        float mag = a[r].x * a[r].x + a[r].y * a[r].y;
        zz += (r & m) ? -mag : mag;
        if (!(r & m)) {
          int r1 = r | m;
          xr += a[r].x * a[r1].x + a[r].y * a[r1].y;
          xi += a[r].x * a[r1].y - a[r].y * a[r1].x;
        }
      }
    } else {
      const int lm = 1 << p;
      bool lo = !(lane & lm);
#pragma unroll
      for (int r = 0; r < 16; ++r) {
        float mag = a[r].x * a[r].x + a[r].y * a[r].y;
        zz += lo ? mag : -mag;
        float pr = __shfl_xor(a[r].x, lm);
        float pi = __shfl_xor(a[r].y, lm);
        if (lo) {
          xr += a[r].x * pr + a[r].y * pi;
          xi += a[r].x * pi - a[r].y * pr;
        }
      }
    }
    prt[w]      = xr;
    prt[10 + w] = xi;
    prt[20 + w] = zz;
  }

  // LDS transpose reduce: stride 65 -> conflict-free rows; slab is free now.
  float* tb = (float*)slabs[wvu];   // 2048 floats
#pragma unroll
  for (int v = 0; v < 30; ++v) tb[v * 65 + lane] = prt[v];
  WAITLDS;
  if (lane < 30) {
    float s = 0.f;
#pragma unroll
    for (int k = 0; k < 64; ++k) s += tb[lane * 65 + k];
    float sc = (lane < 20) ? 2.f : 1.f;
    out[b * 30 + lane] = sc * s;
  }
}

// ------------------------- launch ------------------------------------------

extern "C" void kernel_launch(void* const* d_in, const int* in_sizes, int n_in,
                              void* d_out, int out_size, void* d_ws, size_t ws_size,
                              hipStream_t stream) {
  const float* emb    = (const float*)d_in[0];
  const float* W      = (const float*)d_in[1];
  const float* bias   = (const float*)d_in[2];
  const float* lcu_re = (const float*)d_in[3];
  const float* lcu_im = (const float*)d_in[4];
  const float* qsvt   = (const float*)d_in[5];
  const float* ffp    = (const float*)d_in[6];
  float* out = (float*)d_out;

  char* ws = (char*)d_ws;
  // cs[4096][40] f2 | ffcs[40] | lcu[32] | pad |
  // part1[4][128][1024] v2f (4 MB) | part2[4][128][1024] v2f (4 MB)
  float2* cs    = (float2*)ws;                               // 1,310,720 B
  float2* ffcs  = (float2*)(ws + 1310720);                   //       320 B
  float2* lcu   = (float2*)(ws + 1311040);                   //       256 B
  v2f*    part1 = (v2f*)(ws + 1311744);                      // 4,194,304 B
  v2f*    part2 = (v2f*)(ws + 1311744 + 4194304);            // 4,194,304 B

  params_kernel<<<257, 256, 0, stream>>>(emb, W, bias, lcu_re, lcu_im, ffp,
                                         cs, ffcs, lcu);
  pqc_step<true><<<512, 256, 0, stream>>>(cs, lcu, nullptr, part1);
  pqc_step<false><<<512, 256, 0, stream>>>(cs, lcu, part1, part2);
  final_kernel<<<BATCH / 4, 256, 0, stream>>>(part1, part2, qsvt, ffcs, out);
}

// Round 10
// 153.350 us; speedup vs baseline: 1.5249x; 1.5249x over previous
//
#include <hip/hip_runtime.h>
#include <hip/hip_bf16.h>

// ---------------------------------------------------------------------------
// QuixerCore: 10-qubit QSVT/LCU quantum circuit simulator.
// R3: phased-LDS PQC. R4: tiled params GEMM. R5: v2f packed gate math.
// R6: product-state init (step1 skips 10 RYs + 2 remaps). R7: angle prefetch.
// R10: revert to R7 structure (one token/wave, 4096 waves, 16 waves/CU —
//      R8/R9 proved occupancy is the dominant term). Add:
//      (a) wave staggering (s_sleep by (blk+wv)&3) to break the remap-drain
//          convoy across co-resident waves;
//      (b) final measurement via LDS transpose (30 lanes x 64 sums) instead
//          of 30 six-level shuffle chains.
// Canonical layout: n = r*64+lane, wire w at bit 9-w.
// P2 layout: lane bits 0..5 = wires 5,4,6,7,2,3 ; reg bits 6..9 = wires 8,9,0,1.
// P8 layout: wire->bit: w0=1, w1=0, w>=2: bit w.
// ---------------------------------------------------------------------------

#define NQ   10
#define NT   32
#define DM   512
#define BATCH 128
#define NPQC 40
#define DIM  1024
#define NROWS (BATCH * NT)    // 4096
#define PSTRIDE (BATCH * DIM) // elements per partial slice (v2f)

typedef float v2f __attribute__((ext_vector_type(2)));

#define WAITLDS asm volatile("s_waitcnt lgkmcnt(0)" ::: "memory")

__device__ __forceinline__ v2f Jrot(v2f v) {   // (v.y, -v.x)
  return __builtin_shufflevector(v, -v, 1, 2);
}
__device__ __forceinline__ v2f Jc(v2f v) {     // (-v.y, v.x)
  return __builtin_shufflevector(-v, v, 1, 2);
}

// ------------------------- gate primitives ---------------------------------

template<int B>
__device__ __forceinline__ void g_ry(v2f (&a)[16], float c, float s) {
  static_assert(B >= 6, "RY targets must be register bits");
  constexpr int m = 1 << (B - 6);
#pragma unroll
  for (int r = 0; r < 16; ++r) {
    if (!(r & m)) {
      int r1 = r | m;
      v2f a0 = a[r], a1 = a[r1];
      a[r]  = c * a0 - s * a1;
      a[r1] = s * a0 + c * a1;
    }
  }
}

template<int BC, int BT>
__device__ __forceinline__ void g_crx(v2f (&a)[16], int lane, float c, float s) {
  static_assert(BT >= 6, "CRX targets must be register bits");
  constexpr int m = 1 << (BT - 6);
  bool lane_ok = (BC >= 6) || ((lane >> BC) & 1);
  float ce = lane_ok ? c : 1.f;
  float se = lane_ok ? s : 0.f;
#pragma unroll
  for (int r = 0; r < 16; ++r) {
    if (!(r & m)) {
      if constexpr (BC >= 6) { if (!((r >> (BC - 6)) & 1)) continue; }
      int r1 = r | m;
      v2f a0 = a[r], a1 = a[r1];
      a[r]  = ce * a0 + se * Jrot(a1);
      a[r1] = ce * a1 + se * Jrot(a0);
    }
  }
}

// ------------------------- layout remap ------------------------------------
template<int L0, int L1, int L2, int L3>
__device__ __forceinline__ void remap(v2f (&a)[16], v2f* __restrict__ slab,
                                      int lane) {
  constexpr int LM = (1 << L0) | (1 << L1) | (1 << L2) | (1 << L3);
#pragma unroll
  for (int r = 0; r < 16; ++r) {
    int f = 0;
    if (L0 < 4 && (r & 1)) f |= 1 << L0;
    if (L1 < 4 && (r & 2)) f |= 1 << L1;
    if (L2 < 4 && (r & 4)) f |= 1 << L2;
    if (L3 < 4 && (r & 8)) f |= 1 << L3;
    slab[r * 64 + (lane ^ f)] = a[r];
  }
  WAITLDS;
  int la = lane & ~LM & 63;
  la |= ((lane >> L0) & 1) << 6;
  la |= ((lane >> L1) & 1) << 7;
  la |= ((lane >> L2) & 1) << 8;
  la |= ((lane >> L3) & 1) << 9;
  if (L0 < 4) la |= ((lane >> L0) & 1) << L0;
  if (L1 < 4) la |= ((lane >> L1) & 1) << L1;
  if (L2 < 4) la |= ((lane >> L2) & 1) << L2;
  if (L3 < 4) la |= ((lane >> L3) & 1) << L3;
#pragma unroll
  for (int r = 0; r < 16; ++r) {
    int rc = ((r & 1) ? (1 << L0) : 0) | ((r & 2) ? (1 << L1) : 0)
           | ((r & 4) ? (1 << L2) : 0) | ((r & 8) ? (1 << L3) : 0);
    a[r] = slab[la ^ rc];
  }
}

// ------------------------- phased PQC (angle-prefetched) -------------------
template<bool SKIP_HEAD>
__device__ __forceinline__ void apply_pqc_phased(v2f (&a)[16],
    const float2* __restrict__ cs, v2f* __restrict__ slab, int lane) {
#define RYt(B, t)      g_ry<B>(a, t.x, t.y);
#define CXt(BC, BT, t) g_crx<BC, BT>(a, lane, t.x, t.y);
  float2 t10 = cs[10], t11 = cs[11], t12 = cs[12];
  if constexpr (!SKIP_HEAD) {
    float2 t0 = cs[0], t1 = cs[1], t2 = cs[2], t3 = cs[3];
    float2 t4 = cs[4], t5 = cs[5], t6 = cs[6], t7 = cs[7];
    float2 t8 = cs[8], t9 = cs[9];
    RYt(9,t0) RYt(8,t1) RYt(7,t2) RYt(6,t3)
    remap<5,4,3,2>(a, slab, lane);
    RYt(6,t4) RYt(7,t5) RYt(8,t6) RYt(9,t7)
    remap<1,0,2,3>(a, slab, lane);
    RYt(6,t8) RYt(7,t9)
  }
  CXt(7,8,t10) CXt(6,7,t11) CXt(3,6,t12)
  float2 t13 = cs[13], t14 = cs[14], t15 = cs[15], t16 = cs[16];
  remap<1,0,2,3>(a, slab, lane);
  CXt(8,9,t13) CXt(7,8,t14) CXt(6,7,t15) CXt(5,6,t16)
  float2 t17 = cs[17], t18 = cs[18], t19 = cs[19];
  float2 t20 = cs[20], t21 = cs[21], t22 = cs[22], t23 = cs[23];
  remap<2,3,4,5>(a, slab, lane);
  CXt(8,9,t17) CXt(7,8,t18) CXt(6,7,t19)
  RYt(6,t20) RYt(7,t21) RYt(8,t22) RYt(9,t23)
  float2 t24 = cs[24], t25 = cs[25], t26 = cs[26], t27 = cs[27];
  remap<2,3,4,5>(a, slab, lane);
  RYt(6,t24) RYt(7,t25) RYt(8,t26) RYt(9,t27)
  float2 t28 = cs[28], t29 = cs[29];
  float2 t30 = cs[30], t31 = cs[31], t32 = cs[32], t33 = cs[33];
  remap<1,0,2,3>(a, slab, lane);
  RYt(6,t28) RYt(7,t29)
  CXt(7,6,t30) CXt(8,7,t31) CXt(9,8,t32) CXt(4,9,t33)
  float2 t34 = cs[34], t35 = cs[35], t36 = cs[36], t37 = cs[37];
  remap<4,5,1,0>(a, slab, lane);
  CXt(7,6,t34) CXt(8,7,t35) CXt(9,8,t36) CXt(2,9,t37)
  float2 t38 = cs[38], t39 = cs[39];
  remap<2,3,4,5>(a, slab, lane);
  CXt(7,6,t38) CXt(8,7,t39)
#undef RYt
#undef CXt
}

__device__ __forceinline__ int p8_lane_canon(int lane) {
  return (((lane >> 1) & 1) << 9) | ((lane & 1) << 8) | (((lane >> 2) & 1) << 7)
       | (((lane >> 3) & 1) << 6) | (((lane >> 4) & 1) << 5) | (((lane >> 5) & 1) << 4);
}

// wave-uniform start stagger: break the remap-drain convoy across waves
__device__ __forceinline__ void stagger(int key) {
  int s = key & 3;
  if (s & 1) __builtin_amdgcn_s_sleep(1);   // 64 cyc
  if (s & 2) __builtin_amdgcn_s_sleep(2);   // 128 cyc
}

// ------------------------- params: register-tiled GEMM ----------------------
__global__ __launch_bounds__(256) void params_kernel(
    const float* __restrict__ emb, const float* __restrict__ W,
    const float* __restrict__ bias,
    const float* __restrict__ lcu_re, const float* __restrict__ lcu_im,
    const float* __restrict__ ffp,
    float2* __restrict__ cs, float2* __restrict__ ffcs, float2* __restrict__ lcu) {
  int blk = blockIdx.x;
  int tid = threadIdx.x;
  if (blk == 256) {
    if (tid < NPQC) {
      float h = 0.5f * ffp[tid];
      ffcs[tid] = make_float2(cosf(h), sinf(h));
    }
    if (tid == 64) {
      float ssum = 0.f;
      for (int i = 0; i < NT; ++i) {
        float re = lcu_re[i], im = lcu_im[i];
        ssum += sqrtf(re * re + im * im);
      }
      float inv = 1.f / ssum;
      for (int i = 0; i < NT; ++i)
        lcu[i] = make_float2(lcu_re[i] * inv, lcu_im[i] * inv);
    }
    return;
  }

  __shared__ float Asl[16 * 516];   // 33 KB; reused as reduction buffer
  int row0 = blk * 16;

  const float4* eg = (const float4*)(emb + (size_t)row0 * DM);
#pragma unroll
  for (int i = 0; i < 8; ++i) {
    int e = tid + i * 256;
    int r = e >> 7, k4 = e & 127;
    float4 v = eg[e];
    *(float4*)&Asl[r * 516 + k4 * 4] = v;
  }
  __syncthreads();

  int kq = tid >> 6;
  int lane = tid & 63;
  int rg = lane >> 3;
  int cg = lane & 7;

  const float* Ar0 = &Asl[(2 * rg) * 516 + kq * 128];
  const float* Ar1 = Ar0 + 516;
  const float* Bg  = W + (size_t)(5 * cg) * DM + kq * 128;

  float acc[2][5] = {};
#pragma unroll 4
  for (int k = 0; k < 128; k += 4) {
    float4 a0 = *(const float4*)(Ar0 + k);
    float4 a1 = *(const float4*)(Ar1 + k);
#pragma unroll
    for (int j = 0; j < 5; ++j) {
      float4 b = *(const float4*)(Bg + j * DM + k);
      acc[0][j] += a0.x * b.x + a0.y * b.y + a0.z * b.z + a0.w * b.w;
      acc[1][j] += a1.x * b.x + a1.y * b.y + a1.z * b.z + a1.w * b.w;
    }
  }

  __syncthreads();
  float* red = Asl;
#pragma unroll
  for (int i = 0; i < 2; ++i)
#pragma unroll
    for (int j = 0; j < 5; ++j)
      red[kq * 644 + (2 * rg + i) * 40 + 5 * cg + j] = acc[i][j];
  __syncthreads();

  for (int o = tid; o < 640; o += 256) {
    float v = bias[o % 40] + red[o] + red[644 + o] + red[1288 + o] + red[1932 + o];
    float h = 0.5f * v;
    cs[(size_t)blk * 640 + o] = make_float2(cosf(h), sinf(h));
  }
}

// ------------------------- QSVT step ---------------------------------------
// grid = 1024 (b = blk>>3, slice qq = blk&7), block = 256 = 4 waves,
// wave wv -> token l = qq*4+wv. 32 KB LDS -> ~5 blocks (20 waves)/CU.
template<bool FIRST>
__global__ __launch_bounds__(256) void pqc_step(
    const float2* __restrict__ cs, const float2* __restrict__ lcu,
    const v2f* __restrict__ src, v2f* __restrict__ dst) {
  __shared__ v2f slabs[4][1024];   // 32 KB
  int lane = threadIdx.x & 63;
  int wvu = __builtin_amdgcn_readfirstlane(threadIdx.x >> 6);
  int blk = blockIdx.x;
  stagger(blk + wvu);
  int b = blk >> 3, qq = blk & 7;
  int l = qq * 4 + wvu;
  const float2* csrow = cs + (size_t)(b * NT + l) * NPQC;
  v2f* slab = slabs[wvu];

  v2f a[16];
  if constexpr (FIRST) {
    // product state in P2 layout: lane bits 0..5 = wires 5,4,6,7,2,3 ;
    // reg bits 0..3 = wires 8,9,0,1.  RY|0> column: (cos, sin).
    float2 f5 = csrow[5], f4 = csrow[4], f6 = csrow[6], f7 = csrow[7];
    float2 f2 = csrow[2], f3 = csrow[3];
    float2 f8 = csrow[8], f9 = csrow[9], f0 = csrow[0], f1 = csrow[1];
    float lp = ((lane & 1) ? f5.y : f5.x);
    lp *= ((lane & 2) ? f4.y : f4.x);
    lp *= ((lane & 4) ? f6.y : f6.x);
    lp *= ((lane & 8) ? f7.y : f7.x);
    lp *= ((lane & 16) ? f2.y : f2.x);
    lp *= ((lane & 32) ? f3.y : f3.x);
#pragma unroll
    for (int r = 0; r < 16; ++r) {
      float rp = ((r & 1) ? f8.y : f8.x) * ((r & 2) ? f9.y : f9.x)
               * ((r & 4) ? f0.y : f0.x) * ((r & 8) ? f1.y : f1.x);
      a[r].x = lp * rp;
      a[r].y = 0.f;
    }
  } else {
    const v2f* s = src + (size_t)b * DIM;
#pragma unroll
    for (int r = 0; r < 16; ++r) {
      int n = r * 64 + lane;
      v2f acc = (v2f)(0.f);
#pragma unroll
      for (int q = 0; q < 8; ++q) acc += s[n + q * PSTRIDE];
      a[r] = acc;
    }
  }

  apply_pqc_phased<FIRST>(a, csrow, slab, lane);

  // weighted write into own slab at canonical swizzled index
  float2 w = lcu[l];
  int pl = p8_lane_canon(lane);
  pl ^= (pl >> 5);
#pragma unroll
  for (int r = 0; r < 16; ++r) {
    int rc = ((r & 1) << 3) | ((r & 2) << 1) | ((r & 4) >> 1) | ((r & 8) >> 3); // rev4
    slab[pl ^ rc] = w.x * a[r] + w.y * Jc(a[r]);
  }
  __syncthreads();

  // reduce 4 wave-slabs -> global partial slice (canonical layout)
  v2f* dst_b = dst + (size_t)(qq * BATCH + b) * DIM;
#pragma unroll
  for (int i = 0; i < 4; ++i) {
    int n = threadIdx.x + i * 256;
    int ph = n ^ (n >> 5);
    v2f sum = slabs[0][ph] + slabs[1][ph] + slabs[2][ph] + slabs[3][ph];
    dst_b[n] = sum;
  }
}

// ------------------------- final -------------------------------------------
// 32 blocks x 4 waves (wave = one batch element). LDS-transpose measurement.
__global__ __launch_bounds__(256) void final_kernel(
    const v2f* __restrict__ part1, const v2f* __restrict__ part2,
    const float* __restrict__ qsvt, const float2* __restrict__ ffcs,
    float* __restrict__ out) {
  __shared__ v2f slabs[4][1024];   // 32 KB
  int lane = threadIdx.x & 63;
  int wvu = __builtin_amdgcn_readfirstlane(threadIdx.x >> 6);
  stagger(blockIdx.x + wvu);
  int b = blockIdx.x * 4 + wvu;
  float q0 = qsvt[0], q1 = qsvt[1], q2 = qsvt[2];

  v2f a[16];
  const v2f* p1 = part1 + (size_t)b * DIM;
  const v2f* p2 = part2 + (size_t)b * DIM;
#pragma unroll
  for (int r = 0; r < 16; ++r) {
    int n = r * 64 + lane;
    v2f m1 = (v2f)(0.f), m2 = (v2f)(0.f);
#pragma unroll
    for (int q = 0; q < 8; ++q) {
      m1 += p1[n + q * PSTRIDE];
      m2 += p2[n + q * PSTRIDE];
    }
    a[r] = q1 * m1 + q2 * m2;
  }
  if (lane == 0) a[0].x += q0;

  float nn = 0.f;
#pragma unroll
  for (int r = 0; r < 16; ++r) nn += a[r].x * a[r].x + a[r].y * a[r].y;
#pragma unroll
  for (int o = 1; o < 64; o <<= 1) nn += __shfl_xor(nn, o);
  float inv = 1.f / sqrtf(nn);
#pragma unroll
  for (int r = 0; r < 16; ++r) a[r] *= inv;

  apply_pqc_phased<false>(a, ffcs, slabs[wvu], lane);

  // per-lane partials: prt[w]=X, prt[10+w]=Y, prt[20+w]=Z  (P8 layout)
  constexpr int BPOS[10] = {1, 0, 2, 3, 4, 5, 6, 7, 8, 9};
  float prt[30];
#pragma unroll
  for (int w = 0; w < NQ; ++w) {
    const int p = BPOS[w];
    float xr = 0.f, xi = 0.f, zz = 0.f;
    if (p >= 6) {
      const int m = 1 << (p - 6);
#pragma unroll
      for (int r = 0; r < 16; ++r) {
        float mag = a[r].x * a[r].x + a[r].y * a[r].y;
        zz += (r & m) ? -mag : mag;
        if (!(r & m)) {
          int r1 = r | m;
          xr += a[r].x * a[r1].x + a[r].y * a[r1].y;
          xi += a[r].x * a[r1].y - a[r].y * a[r1].x;
        }
      }
    } else {
      const int lm = 1 << p;
      bool lo = !(lane & lm);
#pragma unroll
      for (int r = 0; r < 16; ++r) {
        float mag = a[r].x * a[r].x + a[r].y * a[r].y;
        zz += lo ? mag : -mag;
        float pr = __shfl_xor(a[r].x, lm);
        float pi = __shfl_xor(a[r].y, lm);
        if (lo) {
          xr += a[r].x * pr + a[r].y * pi;
          xi += a[r].x * pi - a[r].y * pr;
        }
      }
    }
    prt[w]      = xr;
    prt[10 + w] = xi;
    prt[20 + w] = zz;
  }

  // LDS transpose reduce: stride 65 -> conflict-free rows; slab is free now.
  float* tb = (float*)slabs[wvu];   // 2048 floats, need 30*65=1950
#pragma unroll
  for (int v = 0; v < 30; ++v) tb[v * 65 + lane] = prt[v];
  WAITLDS;
  if (lane < 30) {
    float s = 0.f;
#pragma unroll
    for (int k = 0; k < 64; ++k) s += tb[lane * 65 + k];
    float sc = (lane < 20) ? 2.f : 1.f;
    out[b * 30 + lane] = sc * s;
  }
}

// ------------------------- launch ------------------------------------------

extern "C" void kernel_launch(void* const* d_in, const int* in_sizes, int n_in,
                              void* d_out, int out_size, void* d_ws, size_t ws_size,
                              hipStream_t stream) {
  const float* emb    = (const float*)d_in[0];
  const float* W      = (const float*)d_in[1];
  const float* bias   = (const float*)d_in[2];
  const float* lcu_re = (const float*)d_in[3];
  const float* lcu_im = (const float*)d_in[4];
  const float* qsvt   = (const float*)d_in[5];
  const float* ffp    = (const float*)d_in[6];
  float* out = (float*)d_out;

  char* ws = (char*)d_ws;
  // cs[4096][40] f2 | ffcs[40] | lcu[32] | pad |
  // part1[8][128][1024] v2f (8 MB) | part2[8][128][1024] v2f (8 MB)
  float2* cs    = (float2*)ws;                               // 1,310,720 B
  float2* ffcs  = (float2*)(ws + 1310720);                   //       320 B
  float2* lcu   = (float2*)(ws + 1311040);                   //       256 B
  v2f*    part1 = (v2f*)(ws + 1311744);                      // 8,388,608 B
  v2f*    part2 = (v2f*)(ws + 1311744 + 8388608);            // 8,388,608 B

  params_kernel<<<257, 256, 0, stream>>>(emb, W, bias, lcu_re, lcu_im, ffp,
                                         cs, ffcs, lcu);
  pqc_step<true><<<1024, 256, 0, stream>>>(cs, lcu, nullptr, part1);
  pqc_step<false><<<1024, 256, 0, stream>>>(cs, lcu, part1, part2);
  final_kernel<<<BATCH / 4, 256, 0, stream>>>(part1, part2, qsvt, ffcs, out);
}